// Round 2
// baseline (233.652 us; speedup 1.0000x reference)
//
#include <hip/hip_runtime.h>
#include <math.h>

#define DIM 1024
#define NLEVELS 9        // l = 1..9 (l=0 segment of params is a no-op)
#define ROWS_PER_BLOCK 4 // one 64-lane wave per row, 4 waves per block
#define NBLOCKS 2048     // grid-stride over rows; weights amortized per block

// out = exp0( butterfly( log0(x) ) ), C=1:
//   log0(x) = artanh(||x||)/||x|| * x
//   butterfly = per adjacent pair (u[2p],u[2p+1]): z' = (a - i b)_composite * z
//   exp0(y) = tanh(||y||)/||y|| * y
// The composite pair weight is row-independent: product over 9 levels of
// (a_l - i b_l) with (a,b) indexed by j = p >> (l-1) into that level's segment.
__global__ __launch_bounds__(256) void hyper_butterfly_fused(
        const float* __restrict__ x,
        const float* __restrict__ params,
        float* __restrict__ out,
        int rows) {
    const int lane = threadIdx.x & 63;
    const int wave = threadIdx.x >> 6;

    // ---- composite butterfly weights for this lane's 4 float4 slots ----
    // float4 slot idx = lane + 64k holds elements 4*idx..4*idx+3 = pairs
    // 2*idx (W[k].xy) and 2*idx+1 (W[k].zw).
    float4 W[4];
#pragma unroll
    for (int k = 0; k < 4; ++k) {
        const int base_pair = 2 * (lane + 64 * k);
#pragma unroll
        for (int h = 0; h < 2; ++h) {
            const int p = base_pair + h;
            float wr = 1.0f, wi = 0.0f;
            int off = 2 * DIM;  // skip the dead l=0 segment
#pragma unroll
            for (int l = 1; l <= NLEVELS; ++l) {
                const int j = p >> (l - 1);
                const float a = params[off + 2 * j];
                const float b = params[off + 2 * j + 1];
                const float nr = wr * a + wi * b;   // (wr+i wi)*(a-i b)
                const float ni = wi * a - wr * b;
                wr = nr; wi = ni;
                off += 2 * (DIM >> l);
            }
            if (h == 0) { W[k].x = wr; W[k].y = wi; }
            else        { W[k].z = wr; W[k].w = wi; }
        }
    }

    const int row0 = blockIdx.x * ROWS_PER_BLOCK + wave;
    const int row_stride = gridDim.x * ROWS_PER_BLOCK;

    for (int row = row0; row < rows; row += row_stride) {
        const float4* xrow = (const float4*)(x + (size_t)row * DIM);
        float4 v[4];
#pragma unroll
        for (int k = 0; k < 4; ++k) v[k] = xrow[lane + 64 * k];

        // ---- ||x||^2 via pure wave-level xor reduction (no LDS/barrier) ----
        float xn2 = 0.0f;
#pragma unroll
        for (int k = 0; k < 4; ++k)
            xn2 += v[k].x * v[k].x + v[k].y * v[k].y +
                   v[k].z * v[k].z + v[k].w * v[k].w;
#pragma unroll
        for (int m = 32; m > 0; m >>= 1) xn2 += __shfl_xor(xn2, m);

        const float r = sqrtf(xn2);
        const float s1 = (r > 1e-12f)
                             ? (0.5f * logf((1.0f + r) / (1.0f - r)) / r)
                             : 1.0f;

        // ---- scale + complex multiply by composite weights (in place) ----
        float un2 = 0.0f;
#pragma unroll
        for (int k = 0; k < 4; ++k) {
            const float ux = s1 * v[k].x, uy = s1 * v[k].y;
            const float uz = s1 * v[k].z, uw = s1 * v[k].w;
            v[k].x = W[k].x * ux - W[k].y * uy;
            v[k].y = W[k].x * uy + W[k].y * ux;
            v[k].z = W[k].z * uz - W[k].w * uw;
            v[k].w = W[k].z * uw + W[k].w * uz;
            un2 += v[k].x * v[k].x + v[k].y * v[k].y +
                   v[k].z * v[k].z + v[k].w * v[k].w;
        }
#pragma unroll
        for (int m = 32; m > 0; m >>= 1) un2 += __shfl_xor(un2, m);

        const float vn = fmaxf(sqrtf(un2), 1e-8f);
        const float s2 = tanhf(vn) / vn;

        float4* orow = (float4*)(out + (size_t)row * DIM);
#pragma unroll
        for (int k = 0; k < 4; ++k) {
            float4 o;
            o.x = s2 * v[k].x; o.y = s2 * v[k].y;
            o.z = s2 * v[k].z; o.w = s2 * v[k].w;
            orow[lane + 64 * k] = o;
        }
    }
}

extern "C" void kernel_launch(void* const* d_in, const int* in_sizes, int n_in,
                              void* d_out, int out_size, void* d_ws, size_t ws_size,
                              hipStream_t stream) {
    const float* x = (const float*)d_in[0];
    const float* params = (const float*)d_in[1];
    float* out = (float*)d_out;

    const int rows = in_sizes[0] / DIM;
    int nblocks = NBLOCKS;
    const int max_needed = (rows + ROWS_PER_BLOCK - 1) / ROWS_PER_BLOCK;
    if (nblocks > max_needed) nblocks = max_needed;

    hyper_butterfly_fused<<<nblocks, 256, 0, stream>>>(x, params, out, rows);
}

// Round 4
// 231.222 us; speedup vs baseline: 1.0105x; 1.0105x over previous
//
#include <hip/hip_runtime.h>
#include <math.h>

#define DIM 1024
#define NPAIRS 512   // DIM/2
#define NLEVELS 9    // l = 1..9 (l=0 segment of params is a no-op)
#define PAR_OFF (2 * DIM)  // params floats [2048, 4092) hold levels 1..9

// ---------------------------------------------------------------------------
// Kernel 1: collapse the 9 butterfly levels into one complex weight per pair.
// Level l applies z <- (a - i b) * z to z = u[2p] + i u[2p+1], (a,b) shared
// per block of 2^l. Composite weight is row-independent. Runs once, 1 block.
// ---------------------------------------------------------------------------
__global__ void butterfly_weights_kernel(const float* __restrict__ params,
                                         float2* __restrict__ w) {
#pragma unroll
    for (int h = 0; h < 2; ++h) {
        const int p = threadIdx.x + 256 * h;   // pair index, 0..511
        float wr = 1.0f, wi = 0.0f;
        int off = PAR_OFF;
#pragma unroll
        for (int l = 1; l <= NLEVELS; ++l) {
            const int j = p >> (l - 1);
            const float a = params[off + 2 * j];
            const float b = params[off + 2 * j + 1];
            const float nr = wr * a + wi * b;   // (wr + i wi) * (a - i b)
            const float ni = wi * a - wr * b;
            wr = nr; wi = ni;
            off += 2 * (DIM >> l);
        }
        w[p] = make_float2(wr, wi);
    }
}

// ---------------------------------------------------------------------------
// Kernel 2: one wave per row, no barriers, single fused reduction pass.
//   out = s1*s2 * (W (x) x)   where
//   s1 = artanh(||x||)/||x||,   ||u||^2 = s1^2 * t,
//   t  = sum_p |W_p|^2 * ||z_p||^2   (reduced jointly with ||x||^2),
//   s2 = tanh(||u||)/||u||.
// ---------------------------------------------------------------------------
__global__ __launch_bounds__(256) void hyper_butterfly_main(
        const float* __restrict__ x,
        const float4* __restrict__ w4,   // (wr0,wi0,wr1,wi1) per float4 slot
        float* __restrict__ out,
        int rows) {
    const int lane = threadIdx.x & 63;
    const int wave = threadIdx.x >> 6;
    const int row = blockIdx.x * 4 + wave;
    if (row >= rows) return;

    const float4* xrow = (const float4*)(x + (size_t)row * DIM);
    float4 v[4], W[4];
#pragma unroll
    for (int k = 0; k < 4; ++k) v[k] = xrow[lane + 64 * k];
#pragma unroll
    for (int k = 0; k < 4; ++k) W[k] = w4[lane + 64 * k];

    // ---- joint partials: xn2 = sum x^2 ; t = sum |W_p|^2 * ||z_p||^2 ----
    float xn2 = 0.0f, t = 0.0f;
#pragma unroll
    for (int k = 0; k < 4; ++k) {
        const float n0 = v[k].x * v[k].x + v[k].y * v[k].y;
        const float n1 = v[k].z * v[k].z + v[k].w * v[k].w;
        const float a0 = W[k].x * W[k].x + W[k].y * W[k].y;
        const float a1 = W[k].z * W[k].z + W[k].w * W[k].w;
        xn2 += n0 + n1;
        t   += a0 * n0 + a1 * n1;
    }
#pragma unroll
    for (int m = 32; m > 0; m >>= 1) {
        xn2 += __shfl_xor(xn2, m);
        t   += __shfl_xor(t, m);
    }

    // ---- complex multiply, off the reduction critical path ----
    float4 y[4];
#pragma unroll
    for (int k = 0; k < 4; ++k) {
        y[k].x = W[k].x * v[k].x - W[k].y * v[k].y;
        y[k].y = W[k].x * v[k].y + W[k].y * v[k].x;
        y[k].z = W[k].z * v[k].z - W[k].w * v[k].w;
        y[k].w = W[k].z * v[k].w + W[k].w * v[k].z;
    }

    // ---- scales: s1 = artanh(r)/r ; s2 = tanh(vn)/vn, vn = s1*sqrt(t) ----
    const float r = sqrtf(xn2);
    const float s1 = (r > 1e-12f)
                         ? (0.5f * __logf((1.0f + r) / (1.0f - r)) / r)
                         : 1.0f;
    float vn = fmaxf(s1 * sqrtf(t), 1e-8f);
    float s2;
    if (vn < 1e-4f) {
        s2 = 1.0f - vn * vn * (1.0f / 3.0f);   // tanh(v)/v series
    } else {
        const float e = __expf(2.0f * vn);
        s2 = (e - 1.0f) / ((e + 1.0f) * vn);
    }
    const float sc = s1 * s2;

    float4* orow = (float4*)(out + (size_t)row * DIM);
#pragma unroll
    for (int k = 0; k < 4; ++k) {
        float4 o;
        o.x = sc * y[k].x; o.y = sc * y[k].y;
        o.z = sc * y[k].z; o.w = sc * y[k].w;
        orow[lane + 64 * k] = o;
    }
}

extern "C" void kernel_launch(void* const* d_in, const int* in_sizes, int n_in,
                              void* d_out, int out_size, void* d_ws, size_t ws_size,
                              hipStream_t stream) {
    const float* x = (const float*)d_in[0];
    const float* params = (const float*)d_in[1];
    float* out = (float*)d_out;
    float2* w = (float2*)d_ws;  // 512 * 8 B = 4 KB scratch

    const int rows = in_sizes[0] / DIM;
    const int nblocks = (rows + 3) / 4;  // one 64-lane wave per row

    butterfly_weights_kernel<<<1, 256, 0, stream>>>(params, w);
    hyper_butterfly_main<<<nblocks, 256, 0, stream>>>(x, (const float4*)w, out, rows);
}